// Round 7
// baseline (246.818 us; speedup 1.0000x reference)
//
#include <hip/hip_runtime.h>

namespace {
constexpr int kB  = 2;
constexpr int kL  = 2048;
constexpr int kD  = 1024;
constexpr int kH  = 16;
constexpr int kHD = 64;
constexpr int kM  = kB * kL;      // 4096 total rows
}

typedef _Float16 f16x8 __attribute__((ext_vector_type(8)));
typedef float    f32x16 __attribute__((ext_vector_type(16)));
typedef unsigned int u32;

union Frag16 { uint4 u4; unsigned u[4]; f16x8 v; };

__device__ __forceinline__ unsigned short f2h(float f) {
    return __builtin_bit_cast(unsigned short, (_Float16)f);
}
__device__ __forceinline__ unsigned pk2(float a, float b) {
    return __builtin_bit_cast(unsigned, __builtin_amdgcn_cvt_pkrtz(a, b));
}
__device__ __forceinline__ float max3f(float a, float b, float c) {
    float d;
    asm("v_max3_f32 %0, %1, %2, %3" : "=v"(d) : "v"(a), "v"(b), "v"(c));
    return d;
}

// async 16B global -> LDS (wave-uniform LDS base; HW adds lane*16)
__device__ __forceinline__ void gload16(const void* g, void* l) {
    __builtin_amdgcn_global_load_lds(
        (const __attribute__((address_space(1))) u32*)g,
        (__attribute__((address_space(3))) u32*)(unsigned long long)(__builtin_bit_cast(unsigned long long, l)),
        16, 0, 0);
}

// ---------------------------------------------------------------------------
// cast q,k,v (fp32, M x D) -> fp16, same layout. grid (2048, 3)
// ---------------------------------------------------------------------------
__global__ __launch_bounds__(256) void cast_f16_kernel(
    const float* __restrict__ q, const float* __restrict__ k,
    const float* __restrict__ v, unsigned short* __restrict__ dst)
{
    const float* src = blockIdx.y == 0 ? q : (blockIdx.y == 1 ? k : v);
    unsigned short* d = dst + (size_t)blockIdx.y * ((size_t)kM * kD);
    const size_t i = ((size_t)blockIdx.x * 256 + threadIdx.x) * 8;
    const float4 f0 = *(const float4*)(src + i);
    const float4 f1 = *(const float4*)(src + i + 4);
    _Float16 h[8];
    h[0] = (_Float16)f0.x; h[1] = (_Float16)f0.y;
    h[2] = (_Float16)f0.z; h[3] = (_Float16)f0.w;
    h[4] = (_Float16)f1.x; h[5] = (_Float16)f1.y;
    h[6] = (_Float16)f1.z; h[7] = (_Float16)f1.w;
    *(uint4*)(d + i) = *(uint4*)h;
}

// ---------------------------------------------------------------------------
// transpose-cast W (fp32 [k][n]) -> fp16 Wt [n][k]. grid (16, 16, 4)
// ---------------------------------------------------------------------------
__global__ __launch_bounds__(256) void tcast_kernel(
    const float* __restrict__ W0, const float* __restrict__ W1,
    const float* __restrict__ W2, const float* __restrict__ W3,
    unsigned short* __restrict__ WtBase)
{
    __shared__ _Float16 T[64][68];
    const float* W = blockIdx.z == 0 ? W0 : blockIdx.z == 1 ? W1
                   : blockIdx.z == 2 ? W2 : W3;
    unsigned short* Wt = WtBase + (size_t)blockIdx.z * ((size_t)kD * kD);
    const int k0 = blockIdx.y * 64, n0 = blockIdx.x * 64;
    const int tx = threadIdx.x & 15, ty = threadIdx.x >> 4;
#pragma unroll
    for (int i = 0; i < 4; ++i) {
        const int kk = i * 16 + ty;
        const float4 w = *(const float4*)&W[(size_t)(k0 + kk) * kD + n0 + tx * 4];
        T[tx * 4 + 0][kk] = (_Float16)w.x;
        T[tx * 4 + 1][kk] = (_Float16)w.y;
        T[tx * 4 + 2][kk] = (_Float16)w.z;
        T[tx * 4 + 3][kk] = (_Float16)w.w;
    }
    __syncthreads();
#pragma unroll
    for (int i = 0; i < 4; ++i) {
        const int nn = i * 16 + ty;
        *(ushort4*)&Wt[(size_t)(n0 + nn) * kD + k0 + tx * 4] = *(ushort4*)&T[nn][tx * 4];
    }
}

// ---------------------------------------------------------------------------
// fp16 MFMA GEMM + bias: C = A(M x 1024) @ W + bias, W given transposed [n][k].
// 128x128 tile, BK=64, 4 waves x (64x64), mfma_f32_32x32x16_f16.
// MODE 0: fp32 row-major; MODE 1: fp16 heads (B,H,L,HD); MODE 2: fp16 (B,H,HD,L)
// ---------------------------------------------------------------------------
template <int MODE>
__global__ __launch_bounds__(256) void gemm16_kernel(
    const unsigned short* __restrict__ A, const unsigned short* __restrict__ Wt,
    const float* __restrict__ bias, void* __restrict__ Cv)
{
    __shared__ unsigned short Als[2][128 * 64];
    __shared__ unsigned short Bls[2][128 * 64];

    const int tid = threadIdx.x;
    const int lane = tid & 63;
    const int wid = tid >> 6;
    const int l31 = lane & 31;
    const int hi = lane >> 5;
    const int by = blockIdx.x & 31;
    const int bx = blockIdx.x >> 5;
    const int row0 = by * 128;
    const int col0 = bx * 128;
    const int wr = wid >> 1, wc = wid & 1;

    const int rl = lane >> 3;
    const int sl = lane & 7;
    const int ssrc = (sl ^ rl) * 8;

    const unsigned short* Abase = A + (size_t)(row0 + wid * 32 + rl) * kD + ssrc;
    const unsigned short* Bbase = Wt + (size_t)(col0 + wid * 32 + rl) * kD + ssrc;

    f32x16 acc00{}, acc01{}, acc10{}, acc11{};

    auto stage = [&](int kt, int buf) {
#pragma unroll
        for (int i = 0; i < 4; ++i) {
            gload16(Abase + (size_t)(i * 8) * kD + kt * 64,
                    &Als[buf][(wid * 32 + i * 8) * 64]);
        }
#pragma unroll
        for (int i = 0; i < 4; ++i) {
            gload16(Bbase + (size_t)(i * 8) * kD + kt * 64,
                    &Bls[buf][(wid * 32 + i * 8) * 64]);
        }
    };

    const int ra0 = wr * 64 + l31;
    const int cb0 = wc * 64 + l31;

    stage(0, 0);
    int cur = 0;
    for (int kt = 0; kt < kD / 64; ++kt) {
        __syncthreads();
        if (kt + 1 < kD / 64) stage(kt + 1, cur ^ 1);
#pragma unroll
        for (int ks = 0; ks < 4; ++ks) {
            const int slot = (ks << 1) | hi;
            Frag16 a0, a1, b0, b1;
            a0.u4 = *(const uint4*)&Als[cur][ra0 * 64 + ((slot ^ (ra0 & 7)) << 3)];
            a1.u4 = *(const uint4*)&Als[cur][(ra0 + 32) * 64 + ((slot ^ ((ra0 + 32) & 7)) << 3)];
            b0.u4 = *(const uint4*)&Bls[cur][cb0 * 64 + ((slot ^ (cb0 & 7)) << 3)];
            b1.u4 = *(const uint4*)&Bls[cur][(cb0 + 32) * 64 + ((slot ^ ((cb0 + 32) & 7)) << 3)];
            acc00 = __builtin_amdgcn_mfma_f32_32x32x16_f16(a0.v, b0.v, acc00, 0, 0, 0);
            acc01 = __builtin_amdgcn_mfma_f32_32x32x16_f16(a0.v, b1.v, acc01, 0, 0, 0);
            acc10 = __builtin_amdgcn_mfma_f32_32x32x16_f16(a1.v, b0.v, acc10, 0, 0, 0);
            acc11 = __builtin_amdgcn_mfma_f32_32x32x16_f16(a1.v, b1.v, acc11, 0, 0, 0);
        }
        cur ^= 1;
    }

    // ---- epilogue ----
    const float bias0 = bias[col0 + wc * 64 + l31];
    const float bias1 = bias[col0 + wc * 64 + 32 + l31];

    const f32x16* accs[2][2] = {{&acc00, &acc01}, {&acc10, &acc11}};
#pragma unroll
    for (int rt = 0; rt < 2; ++rt) {
#pragma unroll
        for (int ct = 0; ct < 2; ++ct) {
            const f32x16& acv = *accs[rt][ct];
            const float bb = ct ? bias1 : bias0;
            const int c = col0 + wc * 64 + ct * 32 + l31;
            if (MODE == 2) {
                unsigned short* C = (unsigned short*)Cv;
#pragma unroll
                for (int qd = 0; qd < 4; ++qd) {
                    const int r = row0 + wr * 64 + rt * 32 + 8 * qd + 4 * hi;
                    const int b_ = r >> 11, l_ = r & (kL - 1);
                    ushort4 w;
                    w.x = f2h(acv[4 * qd + 0] + bb);
                    w.y = f2h(acv[4 * qd + 1] + bb);
                    w.z = f2h(acv[4 * qd + 2] + bb);
                    w.w = f2h(acv[4 * qd + 3] + bb);
                    *(ushort4*)&C[((size_t)(b_ * kH + (c >> 6)) * kHD + (c & 63)) * kL + l_] = w;
                }
            } else {
#pragma unroll
                for (int reg = 0; reg < 16; ++reg) {
                    const int r = row0 + wr * 64 + rt * 32 + (reg & 3) + 8 * (reg >> 2) + 4 * hi;
                    const float val = acv[reg] + bb;
                    if (MODE == 0) {
                        ((float*)Cv)[(size_t)r * kD + c] = val;
                    } else {
                        const int b_ = r >> 11, l_ = r & (kL - 1);
                        ((unsigned short*)Cv)[((size_t)(b_ * kH + (c >> 6)) * kL + l_) * kHD + (c & 63)] = f2h(val);
                    }
                }
            }
        }
    }
}

// ---------------------------------------------------------------------------
// MFMA flash attention: 8 waves (512 thr), 4-buffer LDS pipeline with counted
// vmcnt (raw s_barrier; never vmcnt(0) in main loop). Split-K x2, XCD-grouped.
// lsum accumulated on the MFMA pipe via an all-ones A fragment (3rd acc).
// ---------------------------------------------------------------------------
__global__ __launch_bounds__(512, 4) void attn_mfma_kernel(
    const unsigned short* __restrict__ Qh, const unsigned short* __restrict__ Kh,
    const unsigned short* __restrict__ Vt, unsigned short* __restrict__ Opart,
    float2* __restrict__ Stat)
{
    __shared__ unsigned short Kls[4][64 * 64];
    __shared__ unsigned short Vls[4][64 * 64];

    const int lane = threadIdx.x & 63;
    const int wid  = threadIdx.x >> 6;       // 0..7
    const int l31  = lane & 31;
    const int hi   = lane >> 5;

    const int id = blockIdx.x;               // 0..511
    const int j  = id >> 3;                  // 0..63
    const int bh = (id & 7) * 4 + (j >> 4);  // 4 heads per XCD
    const int qt = j & 7;                    // 0..7 (256-row q tiles)
    const int ks = (j >> 3) & 1;             // K half
    const int q = qt * 256 + wid * 32 + l31;

    const size_t qkBase = (size_t)bh * kL * kHD;
    const unsigned short* Qp = Qh + qkBase + (size_t)q * kHD + hi * 8;
    Frag16 qf[4];
#pragma unroll
    for (int d = 0; d < 4; ++d) qf[d].u4 = *(const uint4*)(Qp + d * 16);

    // staging: each wave covers 8 rows (one gload16 per matrix per tile)
    const int srow = wid * 8 + (lane >> 3);
    const int soff = (((lane & 7) ^ (srow & 7)) << 3);
    const unsigned short* Kg = Kh + qkBase + (size_t)srow * kHD + soff;
    const unsigned short* Vg = Vt + (size_t)bh * kHD * kL + (size_t)srow * kL + soff;

    auto stage = [&](int kt, int buf) {
        gload16(Kg + (size_t)(kt * 64) * kHD, &Kls[buf][(wid * 8) * 64]);
        gload16(Vg + kt * 64,                 &Vls[buf][(wid * 8) * 64]);
    };

    f16x8 onesv;
#pragma unroll
    for (int i = 0; i < 8; ++i) onesv[i] = (_Float16)1.0f;

    f32x16 o0{}, o1{}, ls{};
    float m = -1e30f;
    const float cexp = 0.125f * 1.44269504089f;

    const int kt0 = ks * 16;
    stage(kt0 + 0, 0);
    stage(kt0 + 1, 1);

    for (int lt = 0; lt < 16; ++lt) {
        // counted wait: tile lt's loads done; deeper tiles stay in flight
        if (lt < 15) asm volatile("s_waitcnt vmcnt(2)" ::: "memory");
        else         asm volatile("s_waitcnt vmcnt(0)" ::: "memory");
        __builtin_amdgcn_s_barrier();
        if (lt + 2 < 16) stage(kt0 + lt + 2, (lt + 2) & 3);
        const int cur = lt & 3;

        const int rA = l31, rB = l31 + 32;
        f32x16 c0{}, c1{};
        Frag16 kf0[4], kf1[4];
#pragma unroll
        for (int d = 0; d < 4; ++d) {
            const int s = (d << 1) | hi;
            kf0[d].u4 = *(const uint4*)&Kls[cur][rA * 64 + ((s ^ (rA & 7)) << 3)];
            kf1[d].u4 = *(const uint4*)&Kls[cur][rB * 64 + ((s ^ (rB & 7)) << 3)];
        }
        Frag16 vf0[4], vf1[4];
#pragma unroll
        for (int ksl = 0; ksl < 4; ++ksl) {
            const int s = (ksl << 1) | hi;
            vf0[ksl].u4 = *(const uint4*)&Vls[cur][rA * 64 + ((s ^ (rA & 7)) << 3)];
            vf1[ksl].u4 = *(const uint4*)&Vls[cur][rB * 64 + ((s ^ (rB & 7)) << 3)];
        }
        __builtin_amdgcn_s_setprio(1);
#pragma unroll
        for (int d = 0; d < 4; ++d) {
            c0 = __builtin_amdgcn_mfma_f32_32x32x16_f16(kf0[d].v, qf[d].v, c0, 0, 0, 0);
            c1 = __builtin_amdgcn_mfma_f32_32x32x16_f16(kf1[d].v, qf[d].v, c1, 0, 0, 0);
        }
        __builtin_amdgcn_s_setprio(0);

        // ---- online softmax over 64 new keys (max via v_max3 chain)
        float mx = fmaxf(c0[0], c1[0]);
#pragma unroll
        for (int r = 1; r < 16; ++r) mx = max3f(mx, c0[r], c1[r]);
        mx = fmaxf(mx, __shfl_xor(mx, 32));
        if (mx > m + 48.f) {                   // defer-max
            const float corr = __builtin_amdgcn_exp2f((m - mx) * cexp);
            m = mx;
            o0 *= corr;
            o1 *= corr;
            ls *= corr;
        }
        const float mc = m * cexp;

        // ---- P = exp2(c*cexp - mc) packed straight to fp16
        unsigned u0[8], u1[8];
#pragma unroll
        for (int i = 0; i < 8; ++i) {
            u0[i] = pk2(__builtin_amdgcn_exp2f(fmaf(c0[2 * i], cexp, -mc)),
                        __builtin_amdgcn_exp2f(fmaf(c0[2 * i + 1], cexp, -mc)));
            u1[i] = pk2(__builtin_amdgcn_exp2f(fmaf(c1[2 * i], cexp, -mc)),
                        __builtin_amdgcn_exp2f(fmaf(c1[2 * i + 1], cexp, -mc)));
        }
        Frag16 pf[4];
        {
            unsigned t0 = hi ? u0[0] : u0[2];
            unsigned t1 = hi ? u0[1] : u0[3];
            unsigned t2 = hi ? u0[4] : u0[6];
            unsigned t3 = hi ? u0[5] : u0[7];
            const unsigned r0 = __shfl_xor(t0, 32);
            const unsigned r1 = __shfl_xor(t1, 32);
            const unsigned r2 = __shfl_xor(t2, 32);
            const unsigned r3 = __shfl_xor(t3, 32);
            pf[0].u[0] = hi ? r0 : u0[0];
            pf[0].u[1] = hi ? r1 : u0[1];
            pf[0].u[2] = hi ? u0[2] : r0;
            pf[0].u[3] = hi ? u0[3] : r1;
            pf[1].u[0] = hi ? r2 : u0[4];
            pf[1].u[1] = hi ? r3 : u0[5];
            pf[1].u[2] = hi ? u0[6] : r2;
            pf[1].u[3] = hi ? u0[7] : r3;
        }
        {
            unsigned t0 = hi ? u1[0] : u1[2];
            unsigned t1 = hi ? u1[1] : u1[3];
            unsigned t2 = hi ? u1[4] : u1[6];
            unsigned t3 = hi ? u1[5] : u1[7];
            const unsigned r0 = __shfl_xor(t0, 32);
            const unsigned r1 = __shfl_xor(t1, 32);
            const unsigned r2 = __shfl_xor(t2, 32);
            const unsigned r3 = __shfl_xor(t3, 32);
            pf[2].u[0] = hi ? r0 : u1[0];
            pf[2].u[1] = hi ? r1 : u1[1];
            pf[2].u[2] = hi ? u1[2] : r0;
            pf[2].u[3] = hi ? u1[3] : r1;
            pf[3].u[0] = hi ? r2 : u1[4];
            pf[3].u[1] = hi ? r3 : u1[5];
            pf[3].u[2] = hi ? u1[6] : r2;
            pf[3].u[3] = hi ? u1[7] : r3;
        }

        // ---- O^T += V^T @ P^T ; lsum row via ones A-frag (MFMA pipe)
        __builtin_amdgcn_s_setprio(1);
#pragma unroll
        for (int ksl = 0; ksl < 4; ++ksl) {
            o0 = __builtin_amdgcn_mfma_f32_32x32x16_f16(vf0[ksl].v, pf[ksl].v, o0, 0, 0, 0);
            o1 = __builtin_amdgcn_mfma_f32_32x32x16_f16(vf1[ksl].v, pf[ksl].v, o1, 0, 0, 0);
            ls = __builtin_amdgcn_mfma_f32_32x32x16_f16(onesv, pf[ksl].v, ls, 0, 0, 0);
        }
        __builtin_amdgcn_s_setprio(0);
    }

    // ---- epilogue: normalized fp16 partial + stats
    const float lsum = ls[0];
    const size_t prow = (size_t)ks * (32 * kL) + (size_t)bh * kL + q;
    const float inv = 1.f / lsum;
    unsigned short* pp = Opart + prow * kHD;
#pragma unroll
    for (int g = 0; g < 4; ++g) {
        const int d = g * 8 + hi * 4;
        uint2 w0, w1;
        w0.x = pk2(o0[4 * g + 0] * inv, o0[4 * g + 1] * inv);
        w0.y = pk2(o0[4 * g + 2] * inv, o0[4 * g + 3] * inv);
        w1.x = pk2(o1[4 * g + 0] * inv, o1[4 * g + 1] * inv);
        w1.y = pk2(o1[4 * g + 2] * inv, o1[4 * g + 3] * inv);
        *(uint2*)(pp + d) = w0;
        *(uint2*)(pp + 32 + d) = w1;
    }
    if (hi == 0) Stat[prow] = make_float2(m, lsum);
}

// ---------------------------------------------------------------------------
// Merge split-K partials -> fp16 O (B, L, D). grid 2048 x 256.
// ---------------------------------------------------------------------------
__global__ __launch_bounds__(256) void merge_kernel(
    const unsigned short* __restrict__ Opart, const float2* __restrict__ Stat,
    unsigned short* __restrict__ O16)
{
    const int g = blockIdx.x * 256 + threadIdx.x;   // 0 .. 2^19-1
    const int row = g >> 3;                         // bh*2048 + q
    const int d0 = (g & 7) * 8;
    const int bh = row >> 11, q = row & (kL - 1);
    const float2 sa = Stat[row];
    const float2 sb = Stat[32 * kL + row];
    const float cexp = 0.125f * 1.44269504089f;
    const float M = fmaxf(sa.x, sb.x);
    float wa = __builtin_amdgcn_exp2f((sa.x - M) * cexp) * sa.y;
    float wb = __builtin_amdgcn_exp2f((sb.x - M) * cexp) * sb.y;
    const float inv = 1.f / (wa + wb);
    wa *= inv; wb *= inv;

    const unsigned short* pa = Opart + (size_t)row * kHD + d0;
    const unsigned short* pb = pa + (size_t)32 * kL * kHD;
    uint4 ua = *(const uint4*)pa;
    uint4 ub = *(const uint4*)pb;
    _Float16 ha[8], hb[8];
    *(uint4*)ha = ua;
    *(uint4*)hb = ub;
    unsigned out[4];
#pragma unroll
    for (int i = 0; i < 4; ++i) {
        const float v0 = wa * (float)ha[2 * i]     + wb * (float)hb[2 * i];
        const float v1 = wa * (float)ha[2 * i + 1] + wb * (float)hb[2 * i + 1];
        out[i] = pk2(v0, v1);
    }
    const int b_ = bh >> 4, h_ = bh & 15;
    *(uint4*)&O16[((size_t)(b_ * kL + q)) * kD + h_ * kHD + d0] = *(uint4*)out;
}

// ---------------------------------------------------------------------------
extern "C" void kernel_launch(void* const* d_in, const int* in_sizes, int n_in,
                              void* d_out, int out_size, void* d_ws, size_t ws_size,
                              hipStream_t stream)
{
    const float* q  = (const float*)d_in[0];
    const float* k  = (const float*)d_in[1];
    const float* v  = (const float*)d_in[2];
    const float* Wq = (const float*)d_in[3];
    const float* bq = (const float*)d_in[4];
    const float* Wk = (const float*)d_in[5];
    const float* bk = (const float*)d_in[6];
    const float* Wv = (const float*)d_in[7];
    const float* bv = (const float*)d_in[8];
    const float* Wo = (const float*)d_in[9];
    const float* bo = (const float*)d_in[10];
    float* out = (float*)d_out;

    const size_t MD = (size_t)kM * kD;   // 4M elems
    const size_t DD = (size_t)kD * kD;   // 1M elems
    unsigned short* A16 = (unsigned short*)d_ws;
    unsigned short* Wt16 = A16 + 3 * MD;
    unsigned short* Qh16 = Wt16 + 4 * DD;
    unsigned short* Kh16 = Qh16 + MD;
    unsigned short* Vt16 = Kh16 + MD;
    unsigned short* O16   = A16;               // q-cast region (dead after Q-proj)
    unsigned short* Opart = A16 + MD;          // k,v-cast regions (dead after K/V-proj)
    float2*         Stat  = (float2*)Wt16;     // Wq-t region (dead after Q-proj)

    const dim3 blk(256);

    hipLaunchKernelGGL(cast_f16_kernel, dim3(kM * kD / (256 * 8), 3), blk, 0, stream,
                       q, k, v, A16);
    hipLaunchKernelGGL(tcast_kernel, dim3(16, 16, 4), blk, 0, stream,
                       Wq, Wk, Wv, Wo, Wt16);

    hipLaunchKernelGGL((gemm16_kernel<1>), dim3(256), blk, 0, stream,
                       A16, Wt16, bq, (void*)Qh16);
    hipLaunchKernelGGL((gemm16_kernel<1>), dim3(256), blk, 0, stream,
                       A16 + MD, Wt16 + DD, bk, (void*)Kh16);
    hipLaunchKernelGGL((gemm16_kernel<2>), dim3(256), blk, 0, stream,
                       A16 + 2 * MD, Wt16 + 2 * DD, bv, (void*)Vt16);

    hipLaunchKernelGGL(attn_mfma_kernel, dim3(512), dim3(512), 0, stream,
                       Qh16, Kh16, Vt16, Opart, Stat);
    hipLaunchKernelGGL(merge_kernel, dim3(2048), blk, 0, stream,
                       Opart, Stat, O16);

    hipLaunchKernelGGL((gemm16_kernel<0>), dim3(256), blk, 0, stream,
                       O16, Wt16 + 3 * DD, bo, (void*)out);
}

// Round 8
// 142.740 us; speedup vs baseline: 1.7291x; 1.7291x over previous
//
#include <hip/hip_runtime.h>

namespace {
constexpr int kB  = 2;
constexpr int kL  = 2048;
constexpr int kD  = 1024;
constexpr int kH  = 16;
constexpr int kHD = 64;
constexpr int kM  = kB * kL;      // 4096 total rows
}

typedef _Float16 f16x8 __attribute__((ext_vector_type(8)));
typedef float    f32x16 __attribute__((ext_vector_type(16)));
typedef unsigned int u32;

union Frag16 { uint4 u4; unsigned u[4]; f16x8 v; };

__device__ __forceinline__ unsigned short f2h(float f) {
    return __builtin_bit_cast(unsigned short, (_Float16)f);
}
__device__ __forceinline__ unsigned pk2(float a, float b) {
    return __builtin_bit_cast(unsigned, __builtin_amdgcn_cvt_pkrtz(a, b));
}
__device__ __forceinline__ float max3f(float a, float b, float c) {
    float d;
    asm("v_max3_f32 %0, %1, %2, %3" : "=v"(d) : "v"(a), "v"(b), "v"(c));
    return d;
}

// async 16B global -> LDS (wave-uniform LDS base; HW adds lane*16)
__device__ __forceinline__ void gload16(const void* g, void* l) {
    __builtin_amdgcn_global_load_lds(
        (const __attribute__((address_space(1))) u32*)g,
        (__attribute__((address_space(3))) u32*)(unsigned long long)(__builtin_bit_cast(unsigned long long, l)),
        16, 0, 0);
}

// ---------------------------------------------------------------------------
// cast q,k,v (fp32, M x D) -> fp16, same layout. grid (2048, 3)
// ---------------------------------------------------------------------------
__global__ __launch_bounds__(256) void cast_f16_kernel(
    const float* __restrict__ q, const float* __restrict__ k,
    const float* __restrict__ v, unsigned short* __restrict__ dst)
{
    const float* src = blockIdx.y == 0 ? q : (blockIdx.y == 1 ? k : v);
    unsigned short* d = dst + (size_t)blockIdx.y * ((size_t)kM * kD);
    const size_t i = ((size_t)blockIdx.x * 256 + threadIdx.x) * 8;
    const float4 f0 = *(const float4*)(src + i);
    const float4 f1 = *(const float4*)(src + i + 4);
    _Float16 h[8];
    h[0] = (_Float16)f0.x; h[1] = (_Float16)f0.y;
    h[2] = (_Float16)f0.z; h[3] = (_Float16)f0.w;
    h[4] = (_Float16)f1.x; h[5] = (_Float16)f1.y;
    h[6] = (_Float16)f1.z; h[7] = (_Float16)f1.w;
    *(uint4*)(d + i) = *(uint4*)h;
}

// ---------------------------------------------------------------------------
// transpose-cast W (fp32 [k][n]) -> fp16 Wt [n][k]. grid (16, 16, 4)
// ---------------------------------------------------------------------------
__global__ __launch_bounds__(256) void tcast_kernel(
    const float* __restrict__ W0, const float* __restrict__ W1,
    const float* __restrict__ W2, const float* __restrict__ W3,
    unsigned short* __restrict__ WtBase)
{
    __shared__ _Float16 T[64][68];
    const float* W = blockIdx.z == 0 ? W0 : blockIdx.z == 1 ? W1
                   : blockIdx.z == 2 ? W2 : W3;
    unsigned short* Wt = WtBase + (size_t)blockIdx.z * ((size_t)kD * kD);
    const int k0 = blockIdx.y * 64, n0 = blockIdx.x * 64;
    const int tx = threadIdx.x & 15, ty = threadIdx.x >> 4;
#pragma unroll
    for (int i = 0; i < 4; ++i) {
        const int kk = i * 16 + ty;
        const float4 w = *(const float4*)&W[(size_t)(k0 + kk) * kD + n0 + tx * 4];
        T[tx * 4 + 0][kk] = (_Float16)w.x;
        T[tx * 4 + 1][kk] = (_Float16)w.y;
        T[tx * 4 + 2][kk] = (_Float16)w.z;
        T[tx * 4 + 3][kk] = (_Float16)w.w;
    }
    __syncthreads();
#pragma unroll
    for (int i = 0; i < 4; ++i) {
        const int nn = i * 16 + ty;
        *(ushort4*)&Wt[(size_t)(n0 + nn) * kD + k0 + tx * 4] = *(ushort4*)&T[nn][tx * 4];
    }
}

// ---------------------------------------------------------------------------
// fp16 MFMA GEMM + bias: C = A(M x 1024) @ W + bias, W given transposed [n][k].
// 128x128 tile, BK=64, 4 waves x (64x64), mfma_f32_32x32x16_f16.
// MODE 0: fp32 row-major; MODE 1: fp16 heads (B,H,L,HD); MODE 2: fp16 (B,H,HD,L)
// ---------------------------------------------------------------------------
template <int MODE>
__global__ __launch_bounds__(256) void gemm16_kernel(
    const unsigned short* __restrict__ A, const unsigned short* __restrict__ Wt,
    const float* __restrict__ bias, void* __restrict__ Cv)
{
    __shared__ unsigned short Als[2][128 * 64];
    __shared__ unsigned short Bls[2][128 * 64];

    const int tid = threadIdx.x;
    const int lane = tid & 63;
    const int wid = tid >> 6;
    const int l31 = lane & 31;
    const int hi = lane >> 5;
    const int by = blockIdx.x & 31;
    const int bx = blockIdx.x >> 5;
    const int row0 = by * 128;
    const int col0 = bx * 128;
    const int wr = wid >> 1, wc = wid & 1;

    const int rl = lane >> 3;
    const int sl = lane & 7;
    const int ssrc = (sl ^ rl) * 8;

    const unsigned short* Abase = A + (size_t)(row0 + wid * 32 + rl) * kD + ssrc;
    const unsigned short* Bbase = Wt + (size_t)(col0 + wid * 32 + rl) * kD + ssrc;

    f32x16 acc00{}, acc01{}, acc10{}, acc11{};

    auto stage = [&](int kt, int buf) {
#pragma unroll
        for (int i = 0; i < 4; ++i) {
            gload16(Abase + (size_t)(i * 8) * kD + kt * 64,
                    &Als[buf][(wid * 32 + i * 8) * 64]);
        }
#pragma unroll
        for (int i = 0; i < 4; ++i) {
            gload16(Bbase + (size_t)(i * 8) * kD + kt * 64,
                    &Bls[buf][(wid * 32 + i * 8) * 64]);
        }
    };

    const int ra0 = wr * 64 + l31;
    const int cb0 = wc * 64 + l31;

    stage(0, 0);
    int cur = 0;
    for (int kt = 0; kt < kD / 64; ++kt) {
        __syncthreads();
        if (kt + 1 < kD / 64) stage(kt + 1, cur ^ 1);
#pragma unroll
        for (int ks = 0; ks < 4; ++ks) {
            const int slot = (ks << 1) | hi;
            Frag16 a0, a1, b0, b1;
            a0.u4 = *(const uint4*)&Als[cur][ra0 * 64 + ((slot ^ (ra0 & 7)) << 3)];
            a1.u4 = *(const uint4*)&Als[cur][(ra0 + 32) * 64 + ((slot ^ ((ra0 + 32) & 7)) << 3)];
            b0.u4 = *(const uint4*)&Bls[cur][cb0 * 64 + ((slot ^ (cb0 & 7)) << 3)];
            b1.u4 = *(const uint4*)&Bls[cur][(cb0 + 32) * 64 + ((slot ^ ((cb0 + 32) & 7)) << 3)];
            acc00 = __builtin_amdgcn_mfma_f32_32x32x16_f16(a0.v, b0.v, acc00, 0, 0, 0);
            acc01 = __builtin_amdgcn_mfma_f32_32x32x16_f16(a0.v, b1.v, acc01, 0, 0, 0);
            acc10 = __builtin_amdgcn_mfma_f32_32x32x16_f16(a1.v, b0.v, acc10, 0, 0, 0);
            acc11 = __builtin_amdgcn_mfma_f32_32x32x16_f16(a1.v, b1.v, acc11, 0, 0, 0);
        }
        cur ^= 1;
    }

    // ---- epilogue ----
    const float bias0 = bias[col0 + wc * 64 + l31];
    const float bias1 = bias[col0 + wc * 64 + 32 + l31];

    const f32x16* accs[2][2] = {{&acc00, &acc01}, {&acc10, &acc11}};
#pragma unroll
    for (int rt = 0; rt < 2; ++rt) {
#pragma unroll
        for (int ct = 0; ct < 2; ++ct) {
            const f32x16& acv = *accs[rt][ct];
            const float bb = ct ? bias1 : bias0;
            const int c = col0 + wc * 64 + ct * 32 + l31;
            if (MODE == 2) {
                unsigned short* C = (unsigned short*)Cv;
#pragma unroll
                for (int qd = 0; qd < 4; ++qd) {
                    const int r = row0 + wr * 64 + rt * 32 + 8 * qd + 4 * hi;
                    const int b_ = r >> 11, l_ = r & (kL - 1);
                    ushort4 w;
                    w.x = f2h(acv[4 * qd + 0] + bb);
                    w.y = f2h(acv[4 * qd + 1] + bb);
                    w.z = f2h(acv[4 * qd + 2] + bb);
                    w.w = f2h(acv[4 * qd + 3] + bb);
                    *(ushort4*)&C[((size_t)(b_ * kH + (c >> 6)) * kHD + (c & 63)) * kL + l_] = w;
                }
            } else {
#pragma unroll
                for (int reg = 0; reg < 16; ++reg) {
                    const int r = row0 + wr * 64 + rt * 32 + (reg & 3) + 8 * (reg >> 2) + 4 * hi;
                    const float val = acv[reg] + bb;
                    if (MODE == 0) {
                        ((float*)Cv)[(size_t)r * kD + c] = val;
                    } else {
                        const int b_ = r >> 11, l_ = r & (kL - 1);
                        ((unsigned short*)Cv)[((size_t)(b_ * kH + (c >> 6)) * kL + l_) * kHD + (c & 63)] = f2h(val);
                    }
                }
            }
        }
    }
}

// ---------------------------------------------------------------------------
// MFMA flash attention: 8 waves (512 thr), 4-buffer LDS pipeline with counted
// vmcnt (raw s_barrier; never vmcnt(0) in main loop). Split-K x2, XCD-grouped.
// lsum accumulated on the MFMA pipe via an all-ones A fragment (3rd acc).
// Plain __launch_bounds__(512): r7's (512,4) capped VGPR at 64 -> scratch
// spill (322MB FETCH). Compiler needs ~110 regs; <=128 keeps 2 blocks/CU.
// ---------------------------------------------------------------------------
__global__ __launch_bounds__(512) void attn_mfma_kernel(
    const unsigned short* __restrict__ Qh, const unsigned short* __restrict__ Kh,
    const unsigned short* __restrict__ Vt, unsigned short* __restrict__ Opart,
    float2* __restrict__ Stat)
{
    __shared__ unsigned short Kls[4][64 * 64];
    __shared__ unsigned short Vls[4][64 * 64];

    const int lane = threadIdx.x & 63;
    const int wid  = threadIdx.x >> 6;       // 0..7
    const int l31  = lane & 31;
    const int hi   = lane >> 5;

    const int id = blockIdx.x;               // 0..511
    const int j  = id >> 3;                  // 0..63
    const int bh = (id & 7) * 4 + (j >> 4);  // 4 heads per XCD
    const int qt = j & 7;                    // 0..7 (256-row q tiles)
    const int ks = (j >> 3) & 1;             // K half
    const int q = qt * 256 + wid * 32 + l31;

    const size_t qkBase = (size_t)bh * kL * kHD;
    const unsigned short* Qp = Qh + qkBase + (size_t)q * kHD + hi * 8;
    Frag16 qf[4];
#pragma unroll
    for (int d = 0; d < 4; ++d) qf[d].u4 = *(const uint4*)(Qp + d * 16);

    // staging: each wave covers 8 rows (one gload16 per matrix per tile)
    const int srow = wid * 8 + (lane >> 3);
    const int soff = (((lane & 7) ^ (srow & 7)) << 3);
    const unsigned short* Kg = Kh + qkBase + (size_t)srow * kHD + soff;
    const unsigned short* Vg = Vt + (size_t)bh * kHD * kL + (size_t)srow * kL + soff;

    auto stage = [&](int kt, int buf) {
        gload16(Kg + (size_t)(kt * 64) * kHD, &Kls[buf][(wid * 8) * 64]);
        gload16(Vg + kt * 64,                 &Vls[buf][(wid * 8) * 64]);
    };

    f16x8 onesv;
#pragma unroll
    for (int i = 0; i < 8; ++i) onesv[i] = (_Float16)1.0f;

    f32x16 o0{}, o1{}, ls{};
    float m = -1e30f;
    const float cexp = 0.125f * 1.44269504089f;

    const int kt0 = ks * 16;
    stage(kt0 + 0, 0);
    stage(kt0 + 1, 1);

    for (int lt = 0; lt < 16; ++lt) {
        // counted wait: tile lt's loads done; deeper tiles stay in flight
        if (lt < 15) asm volatile("s_waitcnt vmcnt(2)" ::: "memory");
        else         asm volatile("s_waitcnt vmcnt(0)" ::: "memory");
        __builtin_amdgcn_s_barrier();
        if (lt + 2 < 16) stage(kt0 + lt + 2, (lt + 2) & 3);
        const int cur = lt & 3;

        const int rA = l31, rB = l31 + 32;
        f32x16 c0{}, c1{};
        Frag16 kf0[4], kf1[4];
#pragma unroll
        for (int d = 0; d < 4; ++d) {
            const int s = (d << 1) | hi;
            kf0[d].u4 = *(const uint4*)&Kls[cur][rA * 64 + ((s ^ (rA & 7)) << 3)];
            kf1[d].u4 = *(const uint4*)&Kls[cur][rB * 64 + ((s ^ (rB & 7)) << 3)];
        }
        Frag16 vf0[4], vf1[4];
#pragma unroll
        for (int ksl = 0; ksl < 4; ++ksl) {
            const int s = (ksl << 1) | hi;
            vf0[ksl].u4 = *(const uint4*)&Vls[cur][rA * 64 + ((s ^ (rA & 7)) << 3)];
            vf1[ksl].u4 = *(const uint4*)&Vls[cur][rB * 64 + ((s ^ (rB & 7)) << 3)];
        }
        __builtin_amdgcn_s_setprio(1);
#pragma unroll
        for (int d = 0; d < 4; ++d) {
            c0 = __builtin_amdgcn_mfma_f32_32x32x16_f16(kf0[d].v, qf[d].v, c0, 0, 0, 0);
            c1 = __builtin_amdgcn_mfma_f32_32x32x16_f16(kf1[d].v, qf[d].v, c1, 0, 0, 0);
        }
        __builtin_amdgcn_s_setprio(0);

        // ---- online softmax over 64 new keys (max via v_max3 chain)
        float mx = fmaxf(c0[0], c1[0]);
#pragma unroll
        for (int r = 1; r < 16; ++r) mx = max3f(mx, c0[r], c1[r]);
        mx = fmaxf(mx, __shfl_xor(mx, 32));
        if (mx > m + 48.f) {                   // defer-max
            const float corr = __builtin_amdgcn_exp2f((m - mx) * cexp);
            m = mx;
            o0 *= corr;
            o1 *= corr;
            ls *= corr;
        }
        const float mc = m * cexp;

        // ---- P = exp2(c*cexp - mc) packed straight to fp16
        unsigned u0[8], u1[8];
#pragma unroll
        for (int i = 0; i < 8; ++i) {
            u0[i] = pk2(__builtin_amdgcn_exp2f(fmaf(c0[2 * i], cexp, -mc)),
                        __builtin_amdgcn_exp2f(fmaf(c0[2 * i + 1], cexp, -mc)));
            u1[i] = pk2(__builtin_amdgcn_exp2f(fmaf(c1[2 * i], cexp, -mc)),
                        __builtin_amdgcn_exp2f(fmaf(c1[2 * i + 1], cexp, -mc)));
        }
        Frag16 pf[4];
        {
            unsigned t0 = hi ? u0[0] : u0[2];
            unsigned t1 = hi ? u0[1] : u0[3];
            unsigned t2 = hi ? u0[4] : u0[6];
            unsigned t3 = hi ? u0[5] : u0[7];
            const unsigned r0 = __shfl_xor(t0, 32);
            const unsigned r1 = __shfl_xor(t1, 32);
            const unsigned r2 = __shfl_xor(t2, 32);
            const unsigned r3 = __shfl_xor(t3, 32);
            pf[0].u[0] = hi ? r0 : u0[0];
            pf[0].u[1] = hi ? r1 : u0[1];
            pf[0].u[2] = hi ? u0[2] : r0;
            pf[0].u[3] = hi ? u0[3] : r1;
            pf[1].u[0] = hi ? r2 : u0[4];
            pf[1].u[1] = hi ? r3 : u0[5];
            pf[1].u[2] = hi ? u0[6] : r2;
            pf[1].u[3] = hi ? u0[7] : r3;
        }
        {
            unsigned t0 = hi ? u1[0] : u1[2];
            unsigned t1 = hi ? u1[1] : u1[3];
            unsigned t2 = hi ? u1[4] : u1[6];
            unsigned t3 = hi ? u1[5] : u1[7];
            const unsigned r0 = __shfl_xor(t0, 32);
            const unsigned r1 = __shfl_xor(t1, 32);
            const unsigned r2 = __shfl_xor(t2, 32);
            const unsigned r3 = __shfl_xor(t3, 32);
            pf[2].u[0] = hi ? r0 : u1[0];
            pf[2].u[1] = hi ? r1 : u1[1];
            pf[2].u[2] = hi ? u1[2] : r0;
            pf[2].u[3] = hi ? u1[3] : r1;
            pf[3].u[0] = hi ? r2 : u1[4];
            pf[3].u[1] = hi ? r3 : u1[5];
            pf[3].u[2] = hi ? u1[6] : r2;
            pf[3].u[3] = hi ? u1[7] : r3;
        }

        // ---- O^T += V^T @ P^T ; lsum row via ones A-frag (MFMA pipe)
        __builtin_amdgcn_s_setprio(1);
#pragma unroll
        for (int ksl = 0; ksl < 4; ++ksl) {
            o0 = __builtin_amdgcn_mfma_f32_32x32x16_f16(vf0[ksl].v, pf[ksl].v, o0, 0, 0, 0);
            o1 = __builtin_amdgcn_mfma_f32_32x32x16_f16(vf1[ksl].v, pf[ksl].v, o1, 0, 0, 0);
            ls = __builtin_amdgcn_mfma_f32_32x32x16_f16(onesv, pf[ksl].v, ls, 0, 0, 0);
        }
        __builtin_amdgcn_s_setprio(0);
    }

    // ---- epilogue: normalized fp16 partial + stats
    const float lsum = ls[0];
    const size_t prow = (size_t)ks * (32 * kL) + (size_t)bh * kL + q;
    const float inv = 1.f / lsum;
    unsigned short* pp = Opart + prow * kHD;
#pragma unroll
    for (int g = 0; g < 4; ++g) {
        const int d = g * 8 + hi * 4;
        uint2 w0, w1;
        w0.x = pk2(o0[4 * g + 0] * inv, o0[4 * g + 1] * inv);
        w0.y = pk2(o0[4 * g + 2] * inv, o0[4 * g + 3] * inv);
        w1.x = pk2(o1[4 * g + 0] * inv, o1[4 * g + 1] * inv);
        w1.y = pk2(o1[4 * g + 2] * inv, o1[4 * g + 3] * inv);
        *(uint2*)(pp + d) = w0;
        *(uint2*)(pp + 32 + d) = w1;
    }
    if (hi == 0) Stat[prow] = make_float2(m, lsum);
}

// ---------------------------------------------------------------------------
// Merge split-K partials -> fp16 O (B, L, D). grid 2048 x 256.
// ---------------------------------------------------------------------------
__global__ __launch_bounds__(256) void merge_kernel(
    const unsigned short* __restrict__ Opart, const float2* __restrict__ Stat,
    unsigned short* __restrict__ O16)
{
    const int g = blockIdx.x * 256 + threadIdx.x;   // 0 .. 2^19-1
    const int row = g >> 3;                         // bh*2048 + q
    const int d0 = (g & 7) * 8;
    const int bh = row >> 11, q = row & (kL - 1);
    const float2 sa = Stat[row];
    const float2 sb = Stat[32 * kL + row];
    const float cexp = 0.125f * 1.44269504089f;
    const float M = fmaxf(sa.x, sb.x);
    float wa = __builtin_amdgcn_exp2f((sa.x - M) * cexp) * sa.y;
    float wb = __builtin_amdgcn_exp2f((sb.x - M) * cexp) * sb.y;
    const float inv = 1.f / (wa + wb);
    wa *= inv; wb *= inv;

    const unsigned short* pa = Opart + (size_t)row * kHD + d0;
    const unsigned short* pb = pa + (size_t)32 * kL * kHD;
    uint4 ua = *(const uint4*)pa;
    uint4 ub = *(const uint4*)pb;
    _Float16 ha[8], hb[8];
    *(uint4*)ha = ua;
    *(uint4*)hb = ub;
    unsigned out[4];
#pragma unroll
    for (int i = 0; i < 4; ++i) {
        const float v0 = wa * (float)ha[2 * i]     + wb * (float)hb[2 * i];
        const float v1 = wa * (float)ha[2 * i + 1] + wb * (float)hb[2 * i + 1];
        out[i] = pk2(v0, v1);
    }
    const int b_ = bh >> 4, h_ = bh & 15;
    *(uint4*)&O16[((size_t)(b_ * kL + q)) * kD + h_ * kHD + d0] = *(uint4*)out;
}

// ---------------------------------------------------------------------------
extern "C" void kernel_launch(void* const* d_in, const int* in_sizes, int n_in,
                              void* d_out, int out_size, void* d_ws, size_t ws_size,
                              hipStream_t stream)
{
    const float* q  = (const float*)d_in[0];
    const float* k  = (const float*)d_in[1];
    const float* v  = (const float*)d_in[2];
    const float* Wq = (const float*)d_in[3];
    const float* bq = (const float*)d_in[4];
    const float* Wk = (const float*)d_in[5];
    const float* bk = (const float*)d_in[6];
    const float* Wv = (const float*)d_in[7];
    const float* bv = (const float*)d_in[8];
    const float* Wo = (const float*)d_in[9];
    const float* bo = (const float*)d_in[10];
    float* out = (float*)d_out;

    const size_t MD = (size_t)kM * kD;   // 4M elems
    const size_t DD = (size_t)kD * kD;   // 1M elems
    unsigned short* A16 = (unsigned short*)d_ws;
    unsigned short* Wt16 = A16 + 3 * MD;
    unsigned short* Qh16 = Wt16 + 4 * DD;
    unsigned short* Kh16 = Qh16 + MD;
    unsigned short* Vt16 = Kh16 + MD;
    unsigned short* O16   = A16;               // q-cast region (dead after Q-proj)
    unsigned short* Opart = A16 + MD;          // k,v-cast regions (dead after K/V-proj)
    float2*         Stat  = (float2*)Wt16;     // Wq-t region (dead after Q-proj)

    const dim3 blk(256);

    hipLaunchKernelGGL(cast_f16_kernel, dim3(kM * kD / (256 * 8), 3), blk, 0, stream,
                       q, k, v, A16);
    hipLaunchKernelGGL(tcast_kernel, dim3(16, 16, 4), blk, 0, stream,
                       Wq, Wk, Wv, Wo, Wt16);

    hipLaunchKernelGGL((gemm16_kernel<1>), dim3(256), blk, 0, stream,
                       A16, Wt16, bq, (void*)Qh16);
    hipLaunchKernelGGL((gemm16_kernel<1>), dim3(256), blk, 0, stream,
                       A16 + MD, Wt16 + DD, bk, (void*)Kh16);
    hipLaunchKernelGGL((gemm16_kernel<2>), dim3(256), blk, 0, stream,
                       A16 + 2 * MD, Wt16 + 2 * DD, bv, (void*)Vt16);

    hipLaunchKernelGGL(attn_mfma_kernel, dim3(512), dim3(512), 0, stream,
                       Qh16, Kh16, Vt16, Opart, Stat);
    hipLaunchKernelGGL(merge_kernel, dim3(2048), blk, 0, stream,
                       Opart, Stat, O16);

    hipLaunchKernelGGL((gemm16_kernel<0>), dim3(256), blk, 0, stream,
                       O16, Wt16 + 3 * DD, bo, (void*)out);
}

// Round 9
// 136.624 us; speedup vs baseline: 1.8065x; 1.0448x over previous
//
#include <hip/hip_runtime.h>

namespace {
constexpr int kB  = 2;
constexpr int kL  = 2048;
constexpr int kD  = 1024;
constexpr int kH  = 16;
constexpr int kHD = 64;
constexpr int kM  = kB * kL;      // 4096 total rows
}

typedef _Float16 f16x8 __attribute__((ext_vector_type(8)));
typedef float    f32x16 __attribute__((ext_vector_type(16)));
typedef unsigned int u32;

union Frag16 { uint4 u4; unsigned u[4]; f16x8 v; };

__device__ __forceinline__ unsigned short f2h(float f) {
    return __builtin_bit_cast(unsigned short, (_Float16)f);
}
__device__ __forceinline__ unsigned pk2(float a, float b) {
    return __builtin_bit_cast(unsigned, __builtin_amdgcn_cvt_pkrtz(a, b));
}
__device__ __forceinline__ float max3f(float a, float b, float c) {
    float d;
    asm("v_max3_f32 %0, %1, %2, %3" : "=v"(d) : "v"(a), "v"(b), "v"(c));
    return d;
}

// async 16B global -> LDS (wave-uniform LDS base; HW adds lane*16)
__device__ __forceinline__ void gload16(const void* g, void* l) {
    __builtin_amdgcn_global_load_lds(
        (const __attribute__((address_space(1))) u32*)g,
        (__attribute__((address_space(3))) u32*)(unsigned long long)(__builtin_bit_cast(unsigned long long, l)),
        16, 0, 0);
}

// ---------------------------------------------------------------------------
// cast q,k,v (fp32, M x D) -> fp16, same layout. grid (2048, 3)
// ---------------------------------------------------------------------------
__global__ __launch_bounds__(256) void cast_f16_kernel(
    const float* __restrict__ q, const float* __restrict__ k,
    const float* __restrict__ v, unsigned short* __restrict__ dst)
{
    const float* src = blockIdx.y == 0 ? q : (blockIdx.y == 1 ? k : v);
    unsigned short* d = dst + (size_t)blockIdx.y * ((size_t)kM * kD);
    const size_t i = ((size_t)blockIdx.x * 256 + threadIdx.x) * 8;
    const float4 f0 = *(const float4*)(src + i);
    const float4 f1 = *(const float4*)(src + i + 4);
    _Float16 h[8];
    h[0] = (_Float16)f0.x; h[1] = (_Float16)f0.y;
    h[2] = (_Float16)f0.z; h[3] = (_Float16)f0.w;
    h[4] = (_Float16)f1.x; h[5] = (_Float16)f1.y;
    h[6] = (_Float16)f1.z; h[7] = (_Float16)f1.w;
    *(uint4*)(d + i) = *(uint4*)h;
}

// ---------------------------------------------------------------------------
// transpose-cast W (fp32 [k][n]) -> fp16 Wt [n][k]. grid (16, 16, 4)
// ---------------------------------------------------------------------------
__global__ __launch_bounds__(256) void tcast_kernel(
    const float* __restrict__ W0, const float* __restrict__ W1,
    const float* __restrict__ W2, const float* __restrict__ W3,
    unsigned short* __restrict__ WtBase)
{
    __shared__ _Float16 T[64][68];
    const float* W = blockIdx.z == 0 ? W0 : blockIdx.z == 1 ? W1
                   : blockIdx.z == 2 ? W2 : W3;
    unsigned short* Wt = WtBase + (size_t)blockIdx.z * ((size_t)kD * kD);
    const int k0 = blockIdx.y * 64, n0 = blockIdx.x * 64;
    const int tx = threadIdx.x & 15, ty = threadIdx.x >> 4;
#pragma unroll
    for (int i = 0; i < 4; ++i) {
        const int kk = i * 16 + ty;
        const float4 w = *(const float4*)&W[(size_t)(k0 + kk) * kD + n0 + tx * 4];
        T[tx * 4 + 0][kk] = (_Float16)w.x;
        T[tx * 4 + 1][kk] = (_Float16)w.y;
        T[tx * 4 + 2][kk] = (_Float16)w.z;
        T[tx * 4 + 3][kk] = (_Float16)w.w;
    }
    __syncthreads();
#pragma unroll
    for (int i = 0; i < 4; ++i) {
        const int nn = i * 16 + ty;
        *(ushort4*)&Wt[(size_t)(n0 + nn) * kD + k0 + tx * 4] = *(ushort4*)&T[nn][tx * 4];
    }
}

// ---------------------------------------------------------------------------
// fp16 MFMA GEMM + bias: C = A(M x 1024) @ W + bias, W given transposed [n][k].
// 128x128 tile, BK=64, 4 waves x (64x64), mfma_f32_32x32x16_f16.
// 3-buffer LDS + counted vmcnt (stage 2 tiles ahead, after the barrier):
// removes the per-K-step vmcnt(0) drain that cost ~6us/gemm with syncthreads.
// MODE 0: fp32 row-major; MODE 1: fp16 heads (B,H,L,HD); MODE 2: fp16 (B,H,HD,L)
// ---------------------------------------------------------------------------
template <int MODE>
__global__ __launch_bounds__(256) void gemm16_kernel(
    const unsigned short* __restrict__ A, const unsigned short* __restrict__ Wt,
    const float* __restrict__ bias, void* __restrict__ Cv)
{
    __shared__ unsigned short Als[3][128 * 64];
    __shared__ unsigned short Bls[3][128 * 64];

    const int tid = threadIdx.x;
    const int lane = tid & 63;
    const int wid = tid >> 6;
    const int l31 = lane & 31;
    const int hi = lane >> 5;
    const int by = blockIdx.x & 31;
    const int bx = blockIdx.x >> 5;
    const int row0 = by * 128;
    const int col0 = bx * 128;
    const int wr = wid >> 1, wc = wid & 1;

    const int rl = lane >> 3;
    const int sl = lane & 7;
    const int ssrc = (sl ^ rl) * 8;

    const unsigned short* Abase = A + (size_t)(row0 + wid * 32 + rl) * kD + ssrc;
    const unsigned short* Bbase = Wt + (size_t)(col0 + wid * 32 + rl) * kD + ssrc;

    f32x16 acc00{}, acc01{}, acc10{}, acc11{};

    auto stage = [&](int kt, int buf) {
#pragma unroll
        for (int i = 0; i < 4; ++i) {
            gload16(Abase + (size_t)(i * 8) * kD + kt * 64,
                    &Als[buf][(wid * 32 + i * 8) * 64]);
        }
#pragma unroll
        for (int i = 0; i < 4; ++i) {
            gload16(Bbase + (size_t)(i * 8) * kD + kt * 64,
                    &Bls[buf][(wid * 32 + i * 8) * 64]);
        }
    };

    const int ra0 = wr * 64 + l31;
    const int cb0 = wc * 64 + l31;

    stage(0, 0);
    stage(1, 1);
    int cur = 0, stg = 2;
    for (int kt = 0; kt < kD / 64; ++kt) {
        // tile kt was staged 2 steps ago (~1200cy): counted wait, no drain
        if (kt < kD / 64 - 1) asm volatile("s_waitcnt vmcnt(8)" ::: "memory");
        else                  asm volatile("s_waitcnt vmcnt(0)" ::: "memory");
        __builtin_amdgcn_s_barrier();
        if (kt + 2 < kD / 64) {     // after barrier: buffer (kt-1)%3 is free
            stage(kt + 2, stg);
            stg = (stg + 1 == 3) ? 0 : stg + 1;
        }
#pragma unroll
        for (int ks = 0; ks < 4; ++ks) {
            const int slot = (ks << 1) | hi;
            Frag16 a0, a1, b0, b1;
            a0.u4 = *(const uint4*)&Als[cur][ra0 * 64 + ((slot ^ (ra0 & 7)) << 3)];
            a1.u4 = *(const uint4*)&Als[cur][(ra0 + 32) * 64 + ((slot ^ ((ra0 + 32) & 7)) << 3)];
            b0.u4 = *(const uint4*)&Bls[cur][cb0 * 64 + ((slot ^ (cb0 & 7)) << 3)];
            b1.u4 = *(const uint4*)&Bls[cur][(cb0 + 32) * 64 + ((slot ^ ((cb0 + 32) & 7)) << 3)];
            acc00 = __builtin_amdgcn_mfma_f32_32x32x16_f16(a0.v, b0.v, acc00, 0, 0, 0);
            acc01 = __builtin_amdgcn_mfma_f32_32x32x16_f16(a0.v, b1.v, acc01, 0, 0, 0);
            acc10 = __builtin_amdgcn_mfma_f32_32x32x16_f16(a1.v, b0.v, acc10, 0, 0, 0);
            acc11 = __builtin_amdgcn_mfma_f32_32x32x16_f16(a1.v, b1.v, acc11, 0, 0, 0);
        }
        cur = (cur + 1 == 3) ? 0 : cur + 1;
    }

    // ---- epilogue ----
    const float bias0 = bias[col0 + wc * 64 + l31];
    const float bias1 = bias[col0 + wc * 64 + 32 + l31];

    const f32x16* accs[2][2] = {{&acc00, &acc01}, {&acc10, &acc11}};
#pragma unroll
    for (int rt = 0; rt < 2; ++rt) {
#pragma unroll
        for (int ct = 0; ct < 2; ++ct) {
            const f32x16& acv = *accs[rt][ct];
            const float bb = ct ? bias1 : bias0;
            const int c = col0 + wc * 64 + ct * 32 + l31;
            if (MODE == 2) {
                unsigned short* C = (unsigned short*)Cv;
#pragma unroll
                for (int qd = 0; qd < 4; ++qd) {
                    const int r = row0 + wr * 64 + rt * 32 + 8 * qd + 4 * hi;
                    const int b_ = r >> 11, l_ = r & (kL - 1);
                    ushort4 w;
                    w.x = f2h(acv[4 * qd + 0] + bb);
                    w.y = f2h(acv[4 * qd + 1] + bb);
                    w.z = f2h(acv[4 * qd + 2] + bb);
                    w.w = f2h(acv[4 * qd + 3] + bb);
                    *(ushort4*)&C[((size_t)(b_ * kH + (c >> 6)) * kHD + (c & 63)) * kL + l_] = w;
                }
            } else {
#pragma unroll
                for (int reg = 0; reg < 16; ++reg) {
                    const int r = row0 + wr * 64 + rt * 32 + (reg & 3) + 8 * (reg >> 2) + 4 * hi;
                    const float val = acv[reg] + bb;
                    if (MODE == 0) {
                        ((float*)Cv)[(size_t)r * kD + c] = val;
                    } else {
                        const int b_ = r >> 11, l_ = r & (kL - 1);
                        ((unsigned short*)Cv)[((size_t)(b_ * kH + (c >> 6)) * kL + l_) * kHD + (c & 63)] = f2h(val);
                    }
                }
            }
        }
    }
}

// ---------------------------------------------------------------------------
// MFMA flash attention: 8 waves (512 thr), 4-buffer LDS; TWO 64-key tiles per
// barrier round (8 rounds) — halves sync-convoy count, and the two tile bodies
// give the scheduler cross-tile ILP (tile B's ds_reads/QK^T hide under tile
// A's softmax). Next pair staged right after the barrier -> a full round
// (~4000cy) in flight, so the vmcnt(0) is prefetch-covered.
// Split-K x2, XCD-grouped; lsum on the MFMA pipe via ones A-frag.
// ---------------------------------------------------------------------------
__global__ __launch_bounds__(512) void attn_mfma_kernel(
    const unsigned short* __restrict__ Qh, const unsigned short* __restrict__ Kh,
    const unsigned short* __restrict__ Vt, unsigned short* __restrict__ Opart,
    float2* __restrict__ Stat)
{
    __shared__ unsigned short Kls[4][64 * 64];
    __shared__ unsigned short Vls[4][64 * 64];

    const int lane = threadIdx.x & 63;
    const int wid  = threadIdx.x >> 6;       // 0..7
    const int l31  = lane & 31;
    const int hi   = lane >> 5;

    const int id = blockIdx.x;               // 0..511
    const int j  = id >> 3;                  // 0..63
    const int bh = (id & 7) * 4 + (j >> 4);  // 4 heads per XCD
    const int qt = j & 7;                    // 0..7 (256-row q tiles)
    const int ks = (j >> 3) & 1;             // K half
    const int q = qt * 256 + wid * 32 + l31;

    const size_t qkBase = (size_t)bh * kL * kHD;
    const unsigned short* Qp = Qh + qkBase + (size_t)q * kHD + hi * 8;
    Frag16 qf[4];
#pragma unroll
    for (int d = 0; d < 4; ++d) qf[d].u4 = *(const uint4*)(Qp + d * 16);

    // staging: each wave covers 8 rows (one gload16 per matrix per tile)
    const int srow = wid * 8 + (lane >> 3);
    const int soff = (((lane & 7) ^ (srow & 7)) << 3);
    const unsigned short* Kg = Kh + qkBase + (size_t)srow * kHD + soff;
    const unsigned short* Vg = Vt + (size_t)bh * kHD * kL + (size_t)srow * kL + soff;

    auto stage = [&](int kt, int buf) {
        gload16(Kg + (size_t)(kt * 64) * kHD, &Kls[buf][(wid * 8) * 64]);
        gload16(Vg + kt * 64,                 &Vls[buf][(wid * 8) * 64]);
    };

    f16x8 onesv;
#pragma unroll
    for (int i = 0; i < 8; ++i) onesv[i] = (_Float16)1.0f;

    f32x16 o0{}, o1{}, ls{};
    float m = -1e30f;
    const float cexp = 0.125f * 1.44269504089f;

    // process one staged 64-key tile (QK^T -> online softmax -> PV)
    auto process = [&](int cur) {
        const int rA = l31, rB = l31 + 32;
        f32x16 c0{}, c1{};
        Frag16 kf0[4], kf1[4];
#pragma unroll
        for (int d = 0; d < 4; ++d) {
            const int s = (d << 1) | hi;
            kf0[d].u4 = *(const uint4*)&Kls[cur][rA * 64 + ((s ^ (rA & 7)) << 3)];
            kf1[d].u4 = *(const uint4*)&Kls[cur][rB * 64 + ((s ^ (rB & 7)) << 3)];
        }
        Frag16 vf0[4], vf1[4];
#pragma unroll
        for (int ksl = 0; ksl < 4; ++ksl) {
            const int s = (ksl << 1) | hi;
            vf0[ksl].u4 = *(const uint4*)&Vls[cur][rA * 64 + ((s ^ (rA & 7)) << 3)];
            vf1[ksl].u4 = *(const uint4*)&Vls[cur][rB * 64 + ((s ^ (rB & 7)) << 3)];
        }
        __builtin_amdgcn_s_setprio(1);
#pragma unroll
        for (int d = 0; d < 4; ++d) {
            c0 = __builtin_amdgcn_mfma_f32_32x32x16_f16(kf0[d].v, qf[d].v, c0, 0, 0, 0);
            c1 = __builtin_amdgcn_mfma_f32_32x32x16_f16(kf1[d].v, qf[d].v, c1, 0, 0, 0);
        }
        __builtin_amdgcn_s_setprio(0);

        // online softmax over 64 new keys (max via v_max3 chain)
        float mx = fmaxf(c0[0], c1[0]);
#pragma unroll
        for (int r = 1; r < 16; ++r) mx = max3f(mx, c0[r], c1[r]);
        mx = fmaxf(mx, __shfl_xor(mx, 32));
        if (mx > m + 48.f) {                   // defer-max
            const float corr = __builtin_amdgcn_exp2f((m - mx) * cexp);
            m = mx;
            o0 *= corr;
            o1 *= corr;
            ls *= corr;
        }
        const float mc = m * cexp;

        // P = exp2(c*cexp - mc) packed straight to fp16
        unsigned u0[8], u1[8];
#pragma unroll
        for (int i = 0; i < 8; ++i) {
            u0[i] = pk2(__builtin_amdgcn_exp2f(fmaf(c0[2 * i], cexp, -mc)),
                        __builtin_amdgcn_exp2f(fmaf(c0[2 * i + 1], cexp, -mc)));
            u1[i] = pk2(__builtin_amdgcn_exp2f(fmaf(c1[2 * i], cexp, -mc)),
                        __builtin_amdgcn_exp2f(fmaf(c1[2 * i + 1], cexp, -mc)));
        }
        Frag16 pf[4];
        {
            unsigned t0 = hi ? u0[0] : u0[2];
            unsigned t1 = hi ? u0[1] : u0[3];
            unsigned t2 = hi ? u0[4] : u0[6];
            unsigned t3 = hi ? u0[5] : u0[7];
            const unsigned r0 = __shfl_xor(t0, 32);
            const unsigned r1 = __shfl_xor(t1, 32);
            const unsigned r2 = __shfl_xor(t2, 32);
            const unsigned r3 = __shfl_xor(t3, 32);
            pf[0].u[0] = hi ? r0 : u0[0];
            pf[0].u[1] = hi ? r1 : u0[1];
            pf[0].u[2] = hi ? u0[2] : r0;
            pf[0].u[3] = hi ? u0[3] : r1;
            pf[1].u[0] = hi ? r2 : u0[4];
            pf[1].u[1] = hi ? r3 : u0[5];
            pf[1].u[2] = hi ? u0[6] : r2;
            pf[1].u[3] = hi ? u0[7] : r3;
        }
        {
            unsigned t0 = hi ? u1[0] : u1[2];
            unsigned t1 = hi ? u1[1] : u1[3];
            unsigned t2 = hi ? u1[4] : u1[6];
            unsigned t3 = hi ? u1[5] : u1[7];
            const unsigned r0 = __shfl_xor(t0, 32);
            const unsigned r1 = __shfl_xor(t1, 32);
            const unsigned r2 = __shfl_xor(t2, 32);
            const unsigned r3 = __shfl_xor(t3, 32);
            pf[2].u[0] = hi ? r0 : u1[0];
            pf[2].u[1] = hi ? r1 : u1[1];
            pf[2].u[2] = hi ? u1[2] : r0;
            pf[2].u[3] = hi ? u1[3] : r1;
            pf[3].u[0] = hi ? r2 : u1[4];
            pf[3].u[1] = hi ? r3 : u1[5];
            pf[3].u[2] = hi ? u1[6] : r2;
            pf[3].u[3] = hi ? u1[7] : r3;
        }

        // O^T += V^T @ P^T ; lsum row via ones A-frag (MFMA pipe)
        __builtin_amdgcn_s_setprio(1);
#pragma unroll
        for (int ksl = 0; ksl < 4; ++ksl) {
            o0 = __builtin_amdgcn_mfma_f32_32x32x16_f16(vf0[ksl].v, pf[ksl].v, o0, 0, 0, 0);
            o1 = __builtin_amdgcn_mfma_f32_32x32x16_f16(vf1[ksl].v, pf[ksl].v, o1, 0, 0, 0);
            ls = __builtin_amdgcn_mfma_f32_32x32x16_f16(onesv, pf[ksl].v, ls, 0, 0, 0);
        }
        __builtin_amdgcn_s_setprio(0);
    };

    const int kt0 = ks * 16;
    stage(kt0 + 0, 0);
    stage(kt0 + 1, 1);

    for (int rt = 0; rt < 8; ++rt) {
        const int t0 = 2 * rt;
        // pair {t0,t0+1} was staged one full round ago -> wait is covered
        asm volatile("s_waitcnt vmcnt(0)" ::: "memory");
        __builtin_amdgcn_s_barrier();
        if (t0 + 3 < 16) {                    // stage next pair into freed bufs
            stage(kt0 + t0 + 2, (t0 + 2) & 3);
            stage(kt0 + t0 + 3, (t0 + 3) & 3);
        }
        process(t0 & 3);
        process((t0 + 1) & 3);
    }

    // ---- epilogue: normalized fp16 partial + stats
    const float lsum = ls[0];
    const size_t prow = (size_t)ks * (32 * kL) + (size_t)bh * kL + q;
    const float inv = 1.f / lsum;
    unsigned short* pp = Opart + prow * kHD;
#pragma unroll
    for (int g = 0; g < 4; ++g) {
        const int d = g * 8 + hi * 4;
        uint2 w0, w1;
        w0.x = pk2(o0[4 * g + 0] * inv, o0[4 * g + 1] * inv);
        w0.y = pk2(o0[4 * g + 2] * inv, o0[4 * g + 3] * inv);
        w1.x = pk2(o1[4 * g + 0] * inv, o1[4 * g + 1] * inv);
        w1.y = pk2(o1[4 * g + 2] * inv, o1[4 * g + 3] * inv);
        *(uint2*)(pp + d) = w0;
        *(uint2*)(pp + 32 + d) = w1;
    }
    if (hi == 0) Stat[prow] = make_float2(m, lsum);
}

// ---------------------------------------------------------------------------
// Merge split-K partials -> fp16 O (B, L, D). grid 2048 x 256.
// ---------------------------------------------------------------------------
__global__ __launch_bounds__(256) void merge_kernel(
    const unsigned short* __restrict__ Opart, const float2* __restrict__ Stat,
    unsigned short* __restrict__ O16)
{
    const int g = blockIdx.x * 256 + threadIdx.x;   // 0 .. 2^19-1
    const int row = g >> 3;                         // bh*2048 + q
    const int d0 = (g & 7) * 8;
    const int bh = row >> 11, q = row & (kL - 1);
    const float2 sa = Stat[row];
    const float2 sb = Stat[32 * kL + row];
    const float cexp = 0.125f * 1.44269504089f;
    const float M = fmaxf(sa.x, sb.x);
    float wa = __builtin_amdgcn_exp2f((sa.x - M) * cexp) * sa.y;
    float wb = __builtin_amdgcn_exp2f((sb.x - M) * cexp) * sb.y;
    const float inv = 1.f / (wa + wb);
    wa *= inv; wb *= inv;

    const unsigned short* pa = Opart + (size_t)row * kHD + d0;
    const unsigned short* pb = pa + (size_t)32 * kL * kHD;
    uint4 ua = *(const uint4*)pa;
    uint4 ub = *(const uint4*)pb;
    _Float16 ha[8], hb[8];
    *(uint4*)ha = ua;
    *(uint4*)hb = ub;
    unsigned out[4];
#pragma unroll
    for (int i = 0; i < 4; ++i) {
        const float v0 = wa * (float)ha[2 * i]     + wb * (float)hb[2 * i];
        const float v1 = wa * (float)ha[2 * i + 1] + wb * (float)hb[2 * i + 1];
        out[i] = pk2(v0, v1);
    }
    const int b_ = bh >> 4, h_ = bh & 15;
    *(uint4*)&O16[((size_t)(b_ * kL + q)) * kD + h_ * kHD + d0] = *(uint4*)out;
}

// ---------------------------------------------------------------------------
extern "C" void kernel_launch(void* const* d_in, const int* in_sizes, int n_in,
                              void* d_out, int out_size, void* d_ws, size_t ws_size,
                              hipStream_t stream)
{
    const float* q  = (const float*)d_in[0];
    const float* k  = (const float*)d_in[1];
    const float* v  = (const float*)d_in[2];
    const float* Wq = (const float*)d_in[3];
    const float* bq = (const float*)d_in[4];
    const float* Wk = (const float*)d_in[5];
    const float* bk = (const float*)d_in[6];
    const float* Wv = (const float*)d_in[7];
    const float* bv = (const float*)d_in[8];
    const float* Wo = (const float*)d_in[9];
    const float* bo = (const float*)d_in[10];
    float* out = (float*)d_out;

    const size_t MD = (size_t)kM * kD;   // 4M elems
    const size_t DD = (size_t)kD * kD;   // 1M elems
    unsigned short* A16 = (unsigned short*)d_ws;
    unsigned short* Wt16 = A16 + 3 * MD;
    unsigned short* Qh16 = Wt16 + 4 * DD;
    unsigned short* Kh16 = Qh16 + MD;
    unsigned short* Vt16 = Kh16 + MD;
    unsigned short* O16   = A16;               // q-cast region (dead after Q-proj)
    unsigned short* Opart = A16 + MD;          // k,v-cast regions (dead after K/V-proj)
    float2*         Stat  = (float2*)Wt16;     // Wq-t region (dead after Q-proj)

    const dim3 blk(256);

    hipLaunchKernelGGL(cast_f16_kernel, dim3(kM * kD / (256 * 8), 3), blk, 0, stream,
                       q, k, v, A16);
    hipLaunchKernelGGL(tcast_kernel, dim3(16, 16, 4), blk, 0, stream,
                       Wq, Wk, Wv, Wo, Wt16);

    hipLaunchKernelGGL((gemm16_kernel<1>), dim3(256), blk, 0, stream,
                       A16, Wt16, bq, (void*)Qh16);
    hipLaunchKernelGGL((gemm16_kernel<1>), dim3(256), blk, 0, stream,
                       A16 + MD, Wt16 + DD, bk, (void*)Kh16);
    hipLaunchKernelGGL((gemm16_kernel<2>), dim3(256), blk, 0, stream,
                       A16 + 2 * MD, Wt16 + 2 * DD, bv, (void*)Vt16);

    hipLaunchKernelGGL(attn_mfma_kernel, dim3(512), dim3(512), 0, stream,
                       Qh16, Kh16, Vt16, Opart, Stat);
    hipLaunchKernelGGL(merge_kernel, dim3(2048), blk, 0, stream,
                       Opart, Stat, O16);

    hipLaunchKernelGGL((gemm16_kernel<0>), dim3(256), blk, 0, stream,
                       O16, Wt16 + 3 * DD, bo, (void*)out);
}